// Round 6
// baseline (330.026 us; speedup 1.0000x reference)
//
#include <hip/hip_runtime.h>

#define H_ 56
#define W_ 56
#define HW_ 3136
#define CIN_ 256
#define COUT_ 256

typedef __attribute__((ext_vector_type(8))) short short8;
typedef __attribute__((ext_vector_type(4))) float f32x4;

// Pre-swizzled bf16 weights, written by prep_weights each launch (idempotent).
// Storage: [bm][kt4][m][u][j] (u = 8-slot index, j = 0..7 within 16B slot);
// storage slot u holds logical k-octet (u ^ (m&7)) of k-tile kt4 (BK=64).
__device__ unsigned short g_wbf[COUT_ * CIN_];

__device__ __forceinline__ unsigned short f2bf(float f) {
  union { float f; unsigned int i; } v; v.f = f;
  unsigned int b = v.i + (0x7fffu + ((v.i >> 16) & 1u));  // RNE
  return (unsigned short)(b >> 16);
}

__device__ __forceinline__ void gload_lds16(const unsigned short* g, unsigned short* l) {
  __builtin_amdgcn_global_load_lds(
      (const __attribute__((address_space(1))) unsigned int*)g,
      (__attribute__((address_space(3))) unsigned int*)l, 16, 0, 0);
}

__global__ __launch_bounds__(256)
void prep_weights(const float* __restrict__ wgt) {
  int idx = blockIdx.x * 256 + threadIdx.x;   // 0..65535
  int bm  = idx >> 15;                        // 0..1
  int kt  = (idx >> 13) & 3;                  // 0..3  (BK=64 tiles)
  int e   = idx & 8191;
  int m   = e >> 6;                           // 0..127
  int u   = (e >> 3) & 7;                     // storage slot
  int j   = e & 7;
  int o   = bm * 128 + m;
  int k   = kt * 64 + (((u ^ (m & 7)) << 3) | j);
  g_wbf[idx] = f2bf(wgt[o * CIN_ + k]);
}

// Branchless masked shifted load: p always dereferenceable at offset 0.
__device__ __forceinline__ float shload(const float* __restrict__ p, bool m, int off) {
  float v = p[m ? off : 0];
  return m ? v : 0.f;
}

__global__ __launch_bounds__(256, 3)
void shiftconv_gemm(const float* __restrict__ x,
                    const float* __restrict__ gamma,
                    const float* __restrict__ beta,
                    const float* __restrict__ rmean,
                    const float* __restrict__ rvar,
                    float* __restrict__ out)
{
  // BK=64: rows are 128B (full 32-bank lines); slot s of row r stored at
  // slot s ^ (r&7)  -> ds_read_b128 frag reads are 2-way banked (free).
  __shared__ unsigned short Alds[2][128 * 64];   // 2 x 16 KB
  __shared__ unsigned short Blds[2][64 * 64];    // 2 x 8 KB
  __shared__ float bnp[256];                     // interleaved (inv, add)

  const int t = threadIdx.x;
  // XCD-bijective swizzle (nwg = 3136 = 8*392): bm-pairs (same bn -> same x
  // slice) land adjacent on the same XCD -> second read is an L2/L3 hit.
  const int orig = blockIdx.x;
  const int wgid = (orig & 7) * 392 + (orig >> 3);
  const int bm   = wgid & 1;     // 2 m-tiles of 128
  const int bn   = wgid >> 1;    // 1568 n-tiles of 64

  const int lane = t & 63;
  const int wv   = t >> 6;
  const int wm   = wv >> 1;      // wave m-half (64 rows)
  const int wn   = wv & 1;       // wave n-half (32 cols)
  const int quad = lane >> 4;
  const int l15  = lane & 15;

  if (t < 128) {
    int o = bm * 128 + t;
    float inv = gamma[o] * rsqrtf(rvar[o] + 1e-5f);
    bnp[2 * t]     = inv;
    bnp[2 * t + 1] = beta[o] - rmean[o] * inv;
  }

  // ---- B staging decode: thread owns 1 n-row x 16 k (k-contiguous) ----
  const int nl    = t & 63;                 // n within tile (= lane)
  // Scalarize the k-group: wave-uniform -> SALU channel/region math.
  const int kg    = __builtin_amdgcn_readfirstlane(t >> 6);   // 0..3
  const int kg16  = kg << 4;
  const int nglob = bn * 64 + nl;
  const int bidx  = nglob / HW_;            // tile lies within one image
  const int rem   = nglob - bidx * HW_;
  const int hh    = rem / W_;
  const int ww    = rem - hh * W_;
  const float* __restrict__ px = x + (size_t)bidx * CIN_ * HW_ + hh * W_ + ww;
  // per-lane edge-validity masks (precomputed once)
  const bool mL = (ww >= 1);          // dx=+1 : y[w]=x[w-1]
  const bool mR = (ww <= W_ - 2);     // dx=-1 : y[w]=x[w+1]
  const bool mU = (hh >= 1);          // dy=+1 : y[h]=x[h-1]
  const bool mD = (hh <= H_ - 2);     // dy=-1 : y[h]=x[h+1]
  const int  h7 = nl & 7;             // B swizzle row bits
  unsigned short* const bpA = &Blds[0][nl * 64];
  unsigned short* const bpB = &Blds[1][nl * 64];

  // ---- A staging source ----
  const unsigned short* wsrc = g_wbf + bm * 32768 + t * 8;

  f32x4 acc[4][2];
  #pragma unroll
  for (int i = 0; i < 4; ++i)
    #pragma unroll
    for (int j = 0; j < 2; ++j)
      acc[i][j] = (f32x4){0.f, 0.f, 0.f, 0.f};

  float fv[16];   // raw x values for next tile (statically indexed)

  // gather 16 channels (shifted, zero-masked) for this thread's n-row
  auto loadB = [&](int kt4) {
    #pragma unroll
    for (int j = 0; j < 16; ++j) {
      int c = kt4 * 64 + kg16 + j;             // wave-uniform channel
      const float* p = px + (size_t)c * HW_;
      float v;
      if (c < 51)       v = p[0];
      else if (c < 102) v = shload(p, mL, -1);
      else if (c < 153) v = shload(p, mR, +1);
      else if (c < 204) v = shload(p, mU, -W_);
      else              v = shload(p, mD, +W_);
      fv[j] = v;
    }
  };
  auto writeB = [&](unsigned short* bp) {
    union { short8 v; unsigned short s[8]; } pa, pb;
    #pragma unroll
    for (int j = 0; j < 8; ++j) { pa.s[j] = f2bf(fv[j]); pb.s[j] = f2bf(fv[8 + j]); }
    int s0 = kg * 2;
    *(short8*)(bp + (((s0    ) ^ h7) << 3)) = pa.v;
    *(short8*)(bp + (((s0 | 1) ^ h7) << 3)) = pb.v;
  };
  auto stageA = [&](int bsel, int kt4) {
    const unsigned short* g = wsrc + kt4 * 8192;
    unsigned short* l = &Alds[bsel][t * 8];
    gload_lds16(g,        l);
    gload_lds16(g + 2048, l + 2048);
    gload_lds16(g + 4096, l + 4096);
    gload_lds16(g + 6144, l + 6144);
  };

  // ---- prologue: stage tile 0 ----
  stageA(0, 0);
  loadB(0);
  writeB(bpA);
  __syncthreads();

  int buf = 0;

  // ---- main loop: 4 K-tiles of 64; one barrier per tile ----
  for (int kt = 0; kt < 4; ++kt) {
    if (kt < 3) {
      stageA(buf ^ 1, kt + 1);
      loadB(kt + 1);
    }

    #pragma unroll
    for (int ks = 0; ks < 2; ++ks) {
      const int sA = ks * 4 + quad;            // logical k-octet slot
      short8 af[4], bfr[2];
      #pragma unroll
      for (int f = 0; f < 4; ++f) {
        int ml = wm * 64 + f * 16 + l15;
        af[f] = *(const short8*)(&Alds[buf][ml * 64 + ((sA ^ (ml & 7)) << 3)]);
      }
      #pragma unroll
      for (int g2 = 0; g2 < 2; ++g2) {
        int nl2 = wn * 32 + g2 * 16 + l15;
        bfr[g2] = *(const short8*)(&Blds[buf][nl2 * 64 + ((sA ^ (nl2 & 7)) << 3)]);
      }
      #pragma unroll
      for (int mf = 0; mf < 4; ++mf)
        #pragma unroll
        for (int nf = 0; nf < 2; ++nf)
          acc[mf][nf] = __builtin_amdgcn_mfma_f32_16x16x32_bf16(
              af[mf], bfr[nf], acc[mf][nf], 0, 0, 0);
    }

    if (kt < 3)
      writeB((buf ^ 1) ? bpB : bpA);

    __syncthreads();
    buf ^= 1;
  }

  // ---- epilogue: BN + ReLU + fp32 store ----
  size_t nbase[2];
  #pragma unroll
  for (int nf = 0; nf < 2; ++nf) {
    int ng  = bn * 64 + wn * 32 + nf * 16 + l15;
    int b2  = ng / HW_;
    int hw2 = ng - b2 * HW_;
    nbase[nf] = (size_t)b2 * COUT_ * HW_ + hw2;
  }
  #pragma unroll
  for (int mf = 0; mf < 4; ++mf) {
    int mloc = wm * 64 + mf * 16 + quad * 4;   // local o for reg r=0
    float inv[4], add[4];
    #pragma unroll
    for (int r = 0; r < 4; ++r) {
      inv[r] = bnp[2 * (mloc + r)];
      add[r] = bnp[2 * (mloc + r) + 1];
    }
    size_t obase = (size_t)(bm * 128 + mloc) * HW_;
    #pragma unroll
    for (int nf = 0; nf < 2; ++nf) {
      #pragma unroll
      for (int r = 0; r < 4; ++r) {
        float v = fmaf(acc[mf][nf][r], inv[r], add[r]);
        out[nbase[nf] + obase + (size_t)r * HW_] = fmaxf(v, 0.0f);
      }
    }
  }
}

extern "C" void kernel_launch(void* const* d_in, const int* in_sizes, int n_in,
                              void* d_out, int out_size, void* d_ws, size_t ws_size,
                              hipStream_t stream) {
  const float* x     = (const float*)d_in[0];
  const float* wgt   = (const float*)d_in[1];
  const float* gamma = (const float*)d_in[2];
  const float* beta  = (const float*)d_in[3];
  const float* rmean = (const float*)d_in[4];
  const float* rvar  = (const float*)d_in[5];
  float* out = (float*)d_out;

  prep_weights<<<dim3(256), dim3(256), 0, stream>>>(wgt);
  shiftconv_gemm<<<dim3(3136), dim3(256), 0, stream>>>(x, gamma, beta, rmean, rvar, out);
}

// Round 7
// 243.082 us; speedup vs baseline: 1.3577x; 1.3577x over previous
//
#include <hip/hip_runtime.h>

#define H_ 56
#define W_ 56
#define HW_ 3136
#define CIN_ 256
#define COUT_ 256

typedef __attribute__((ext_vector_type(8))) short short8;
typedef __attribute__((ext_vector_type(4))) float f32x4;

// Pre-swizzled bf16 weights, written by prep_weights each launch (idempotent).
// Storage: [bm][kt4][m][u][j] (u = 8-slot index, j = 0..7 within 16B slot);
// storage slot u holds logical k-octet (u ^ (m&7)) of k-tile kt4 (BK=64).
__device__ unsigned short g_wbf[COUT_ * CIN_];

__device__ __forceinline__ unsigned short f2bf(float f) {
  union { float f; unsigned int i; } v; v.f = f;
  unsigned int b = v.i + (0x7fffu + ((v.i >> 16) & 1u));  // RNE
  return (unsigned short)(b >> 16);
}

__device__ __forceinline__ void gload_lds16(const unsigned short* g, unsigned short* l) {
  __builtin_amdgcn_global_load_lds(
      (const __attribute__((address_space(1))) unsigned int*)g,
      (__attribute__((address_space(3))) unsigned int*)l, 16, 0, 0);
}

__global__ __launch_bounds__(256)
void prep_weights(const float* __restrict__ wgt) {
  int idx = blockIdx.x * 256 + threadIdx.x;   // 0..65535
  int bm  = idx >> 15;                        // 0..1
  int kt  = (idx >> 13) & 3;                  // 0..3  (BK=64 tiles)
  int e   = idx & 8191;
  int m   = e >> 6;                           // 0..127
  int u   = (e >> 3) & 7;                     // storage slot
  int j   = e & 7;
  int o   = bm * 128 + m;
  int k   = kt * 64 + (((u ^ (m & 7)) << 3) | j);
  g_wbf[idx] = f2bf(wgt[o * CIN_ + k]);
}

__global__ __launch_bounds__(256, 3)
void shiftconv_gemm(const float* __restrict__ x,
                    const float* __restrict__ gamma,
                    const float* __restrict__ beta,
                    const float* __restrict__ rmean,
                    const float* __restrict__ rvar,
                    float* __restrict__ out)
{
  // BK=64: rows are 128B (full 32-bank lines); slot s of row r stored at
  // slot s ^ (r&7)  -> ds_read_b128 frag reads are 2-way banked (free).
  __shared__ unsigned short Alds[2][128 * 64];   // 2 x 16 KB
  __shared__ unsigned short Blds[2][64 * 64];    // 2 x 8 KB
  __shared__ float bnp[256];                     // interleaved (inv, add)

  const int t = threadIdx.x;
  // XCD-bijective swizzle (nwg = 3136 = 8*392): bm-pairs (same bn -> same x
  // slice) land adjacent on the same XCD -> second read is an L2/L3 hit.
  const int orig = blockIdx.x;
  const int wgid = (orig & 7) * 392 + (orig >> 3);
  const int bm   = wgid & 1;     // 2 m-tiles of 128
  const int bn   = wgid >> 1;    // 1568 n-tiles of 64

  const int lane = t & 63;
  const int wv   = t >> 6;
  const int wm   = wv >> 1;      // wave m-half (64 rows)
  const int wn   = wv & 1;       // wave n-half (32 cols)
  const int quad = lane >> 4;
  const int l15  = lane & 15;

  if (t < 128) {
    int o = bm * 128 + t;
    float inv = gamma[o] * rsqrtf(rvar[o] + 1e-5f);
    bnp[2 * t]     = inv;
    bnp[2 * t + 1] = beta[o] - rmean[o] * inv;
  }

  // ---- B staging decode: thread owns 1 n-row x 16 k (k-contiguous) ----
  const int nl    = t & 63;                 // n within tile (= lane)
  // Scalarize the k-group: wave-uniform -> SALU channel/region math.
  const int kg    = __builtin_amdgcn_readfirstlane(t >> 6);   // 0..3
  const int kg16  = kg << 4;
  const int nglob = bn * 64 + nl;
  const int bidx  = nglob / HW_;            // tile lies within one image
  const int rem   = nglob - bidx * HW_;
  const int hh    = rem / W_;
  const int ww    = rem - hh * W_;
  const float* __restrict__ px = x + (size_t)bidx * CIN_ * HW_ + hh * W_ + ww;
  // per-lane edge-validity masks (precomputed once)
  const bool mL = (ww >= 1);          // dx=+1 : y[w]=x[w-1]
  const bool mR = (ww <= W_ - 2);     // dx=-1 : y[w]=x[w+1]
  const bool mU = (hh >= 1);          // dy=+1 : y[h]=x[h-1]
  const bool mD = (hh <= H_ - 2);     // dy=-1 : y[h]=x[h+1]
  const int  h7 = nl & 7;             // B swizzle row bits
  unsigned short* const bpA = &Blds[0][nl * 64];
  unsigned short* const bpB = &Blds[1][nl * 64];

  // ---- A staging source ----
  const unsigned short* wsrc = g_wbf + bm * 32768 + t * 8;

  f32x4 acc[4][2];
  #pragma unroll
  for (int i = 0; i < 4; ++i)
    #pragma unroll
    for (int j = 0; j < 2; ++j)
      acc[i][j] = (f32x4){0.f, 0.f, 0.f, 0.f};

  float fv[16];   // raw x values for next tile (statically indexed)

  // gather 16 channels (shifted, zero-masked) for this thread's n-row.
  // BRANCHLESS: region r is wave-uniform scalar; offset via cselect chain,
  // validity via cndmask chain -> all 16 loads issue in ONE basic block
  // (one vmcnt group, one latency per tile instead of 16).
  auto loadB = [&](int kt4) {
    #pragma unroll
    for (int j = 0; j < 16; ++j) {
      int c = kt4 * 64 + kg16 + j;             // wave-uniform channel
      int r = (c >= 51) + (c >= 102) + (c >= 153) + (c >= 204);   // 0..4
      int off = (r == 1) ? -1 : (r == 2) ? 1 : (r == 3) ? -W_ :
                (r == 4) ? W_ : 0;             // scalar cselect chain
      bool mm = (r == 0) | ((r == 1) & mL) | ((r == 2) & mR) |
                ((r == 3) & mU) | ((r == 4) & mD);
      const float* p = px + (size_t)c * HW_;
      float v = p[mm ? off : 0];               // always dereferenceable
      fv[j] = mm ? v : 0.f;
    }
  };
  auto writeB = [&](unsigned short* bp) {
    union { short8 v; unsigned short s[8]; } pa, pb;
    #pragma unroll
    for (int j = 0; j < 8; ++j) { pa.s[j] = f2bf(fv[j]); pb.s[j] = f2bf(fv[8 + j]); }
    int s0 = kg * 2;
    *(short8*)(bp + (((s0    ) ^ h7) << 3)) = pa.v;
    *(short8*)(bp + (((s0 | 1) ^ h7) << 3)) = pb.v;
  };
  auto stageA = [&](int bsel, int kt4) {
    const unsigned short* g = wsrc + kt4 * 8192;
    unsigned short* l = &Alds[bsel][t * 8];
    gload_lds16(g,        l);
    gload_lds16(g + 2048, l + 2048);
    gload_lds16(g + 4096, l + 4096);
    gload_lds16(g + 6144, l + 6144);
  };

  // ---- prologue: stage tile 0 ----
  stageA(0, 0);
  loadB(0);
  writeB(bpA);
  __syncthreads();

  int buf = 0;

  // ---- main loop: 4 K-tiles of 64; one barrier per tile ----
  for (int kt = 0; kt < 4; ++kt) {
    if (kt < 3) {
      stageA(buf ^ 1, kt + 1);
      loadB(kt + 1);
    }

    #pragma unroll
    for (int ks = 0; ks < 2; ++ks) {
      const int sA = ks * 4 + quad;            // logical k-octet slot
      short8 af[4], bfr[2];
      #pragma unroll
      for (int f = 0; f < 4; ++f) {
        int ml = wm * 64 + f * 16 + l15;
        af[f] = *(const short8*)(&Alds[buf][ml * 64 + ((sA ^ (ml & 7)) << 3)]);
      }
      #pragma unroll
      for (int g2 = 0; g2 < 2; ++g2) {
        int nl2 = wn * 32 + g2 * 16 + l15;
        bfr[g2] = *(const short8*)(&Blds[buf][nl2 * 64 + ((sA ^ (nl2 & 7)) << 3)]);
      }
      #pragma unroll
      for (int mf = 0; mf < 4; ++mf)
        #pragma unroll
        for (int nf = 0; nf < 2; ++nf)
          acc[mf][nf] = __builtin_amdgcn_mfma_f32_16x16x32_bf16(
              af[mf], bfr[nf], acc[mf][nf], 0, 0, 0);
    }

    if (kt < 3)
      writeB((buf ^ 1) ? bpB : bpA);

    __syncthreads();
    buf ^= 1;
  }

  // ---- epilogue: BN + ReLU + fp32 store ----
  size_t nbase[2];
  #pragma unroll
  for (int nf = 0; nf < 2; ++nf) {
    int ng  = bn * 64 + wn * 32 + nf * 16 + l15;
    int b2  = ng / HW_;
    int hw2 = ng - b2 * HW_;
    nbase[nf] = (size_t)b2 * COUT_ * HW_ + hw2;
  }
  #pragma unroll
  for (int mf = 0; mf < 4; ++mf) {
    int mloc = wm * 64 + mf * 16 + quad * 4;   // local o for reg r=0
    float inv[4], add[4];
    #pragma unroll
    for (int r = 0; r < 4; ++r) {
      inv[r] = bnp[2 * (mloc + r)];
      add[r] = bnp[2 * (mloc + r) + 1];
    }
    size_t obase = (size_t)(bm * 128 + mloc) * HW_;
    #pragma unroll
    for (int nf = 0; nf < 2; ++nf) {
      #pragma unroll
      for (int r = 0; r < 4; ++r) {
        float v = fmaf(acc[mf][nf][r], inv[r], add[r]);
        out[nbase[nf] + obase + (size_t)r * HW_] = fmaxf(v, 0.0f);
      }
    }
  }
}

extern "C" void kernel_launch(void* const* d_in, const int* in_sizes, int n_in,
                              void* d_out, int out_size, void* d_ws, size_t ws_size,
                              hipStream_t stream) {
  const float* x     = (const float*)d_in[0];
  const float* wgt   = (const float*)d_in[1];
  const float* gamma = (const float*)d_in[2];
  const float* beta  = (const float*)d_in[3];
  const float* rmean = (const float*)d_in[4];
  const float* rvar  = (const float*)d_in[5];
  float* out = (float*)d_out;

  prep_weights<<<dim3(256), dim3(256), 0, stream>>>(wgt);
  shiftconv_gemm<<<dim3(3136), dim3(256), 0, stream>>>(x, gamma, beta, rmean, rvar, out);
}

// Round 8
// 225.799 us; speedup vs baseline: 1.4616x; 1.0765x over previous
//
#include <hip/hip_runtime.h>

#define H_ 56
#define W_ 56
#define HW_ 3136
#define CIN_ 256
#define COUT_ 256

typedef __attribute__((ext_vector_type(8))) short short8;
typedef __attribute__((ext_vector_type(4))) float f32x4;

// Fragment-ordered bf16 weights (written by prep_weights each launch, idempotent).
// idx = ((((bm*2+wm)*8+ks)*4+f)*64+lane)*8+j  holds
//   W[bm*128 + wm*64 + f*16 + (lane&15)][ks*32 + (lane>>4)*8 + j]
// -> one wave's af[f] load for k-step ks is a contiguous, coalesced 1KB read.
__device__ unsigned short g_wbf[COUT_ * CIN_];

__device__ __forceinline__ unsigned short f2bf(float f) {
  union { float f; unsigned int i; } v; v.f = f;
  unsigned int b = v.i + (0x7fffu + ((v.i >> 16) & 1u));  // RNE
  return (unsigned short)(b >> 16);
}

__global__ __launch_bounds__(256)
void prep_weights(const float* __restrict__ wgt) {
  int idx  = blockIdx.x * 256 + threadIdx.x;   // 0..65535
  int j    = idx & 7;
  int lane = (idx >> 3) & 63;
  int f    = (idx >> 9) & 3;
  int ks   = (idx >> 11) & 7;
  int wm   = (idx >> 14) & 1;
  int bm   = idx >> 15;
  int m = bm * 128 + wm * 64 + f * 16 + (lane & 15);
  int k = ks * 32 + (lane >> 4) * 8 + j;
  g_wbf[idx] = f2bf(wgt[m * CIN_ + k]);
}

__global__ __launch_bounds__(256, 4)
void shiftconv_gemm(const float* __restrict__ x,
                    const float* __restrict__ gamma,
                    const float* __restrict__ beta,
                    const float* __restrict__ rmean,
                    const float* __restrict__ rvar,
                    float* __restrict__ out)
{
  // B only in LDS (A frags come straight from L2-resident g_wbf).
  // BK=64: rows are 128B; slot s of row r stored at s ^ (r&7) -> verified
  // zero bank conflicts (round 6/7 PMC).
  __shared__ unsigned short Blds[2][64 * 64];    // 2 x 8 KB
  __shared__ float bnp[256];                     // interleaved (inv, add)

  const int t = threadIdx.x;
  // XCD-bijective swizzle (nwg = 3136 = 8*392): bm-pairs (same bn -> same x
  // slice) land adjacent on the same XCD -> second read is an L2/L3 hit.
  const int orig = blockIdx.x;
  const int wgid = (orig & 7) * 392 + (orig >> 3);
  const int bm   = wgid & 1;     // 2 m-tiles of 128
  const int bn   = wgid >> 1;    // 1568 n-tiles of 64

  const int lane = t & 63;
  const int wv   = t >> 6;
  const int wm   = wv >> 1;      // wave m-half (64 rows)
  const int wn   = wv & 1;       // wave n-half (32 cols)
  const int quad = lane >> 4;
  const int l15  = lane & 15;

  if (t < 128) {
    int o = bm * 128 + t;
    float inv = gamma[o] * rsqrtf(rvar[o] + 1e-5f);
    bnp[2 * t]     = inv;
    bnp[2 * t + 1] = beta[o] - rmean[o] * inv;
  }

  // ---- B staging decode: thread owns 1 n-row x 16 k (k-contiguous) ----
  const int nl    = t & 63;                 // n within tile (= lane)
  const int kg    = __builtin_amdgcn_readfirstlane(t >> 6);   // 0..3, wave-uniform
  const int kg16  = kg << 4;
  const int nglob = bn * 64 + nl;
  const int bidx  = nglob / HW_;            // tile lies within one image
  const int rem   = nglob - bidx * HW_;
  const int hh    = rem / W_;
  const int ww    = rem - hh * W_;
  const float* __restrict__ px = x + (size_t)bidx * CIN_ * HW_ + hh * W_ + ww;
  // per-lane edge-validity masks (precomputed once)
  const bool mL = (ww >= 1);          // dx=+1 : y[w]=x[w-1]
  const bool mR = (ww <= W_ - 2);     // dx=-1 : y[w]=x[w+1]
  const bool mU = (hh >= 1);          // dy=+1 : y[h]=x[h-1]
  const bool mD = (hh <= H_ - 2);     // dy=-1 : y[h]=x[h+1]
  const int  h7 = nl & 7;             // B swizzle row bits
  unsigned short* const bpA = &Blds[0][nl * 64];
  unsigned short* const bpB = &Blds[1][nl * 64];

  // ---- A fragment source: fragment-ordered bf16 weights in L2 ----
  const unsigned short* afrag = g_wbf + (size_t)(bm * 2 + wm) * 16384 + lane * 8;

  f32x4 acc[4][2];
  #pragma unroll
  for (int i = 0; i < 4; ++i)
    #pragma unroll
    for (int j = 0; j < 2; ++j)
      acc[i][j] = (f32x4){0.f, 0.f, 0.f, 0.f};

  float fv[16];   // raw x values for next tile (statically indexed)

  // gather 16 channels (shifted, zero-masked) for this thread's n-row.
  // BRANCHLESS: region r is wave-uniform scalar (offset via cselect chain,
  // validity via mask-select) -> all 16 loads issue in ONE basic block.
  auto loadB = [&](int kt4) {
    #pragma unroll
    for (int j = 0; j < 16; ++j) {
      int c = kt4 * 64 + kg16 + j;             // wave-uniform channel
      int r = (c >= 51) + (c >= 102) + (c >= 153) + (c >= 204);   // 0..4
      int off = (r == 1) ? -1 : (r == 2) ? 1 : (r == 3) ? -W_ :
                (r == 4) ? W_ : 0;             // scalar cselect chain
      bool mm = (r == 0) | ((r == 1) & mL) | ((r == 2) & mR) |
                ((r == 3) & mU) | ((r == 4) & mD);
      const float* p = px + (size_t)c * HW_;
      float v = p[mm ? off : 0];               // always dereferenceable
      fv[j] = mm ? v : 0.f;
    }
  };
  // pack via v_cvt_pk_bf16_f32 (RNE): 8 instrs replace 64 f2bf VALU ops
  auto writeB = [&](unsigned short* bp) {
    unsigned int da[4], db[4];
    #pragma unroll
    for (int j = 0; j < 4; ++j) {
      asm("v_cvt_pk_bf16_f32 %0, %1, %2" : "=v"(da[j]) : "v"(fv[2*j]),     "v"(fv[2*j+1]));
      asm("v_cvt_pk_bf16_f32 %0, %1, %2" : "=v"(db[j]) : "v"(fv[8+2*j]),   "v"(fv[8+2*j+1]));
    }
    int s0 = kg * 2;
    *(uint4*)(bp + (((s0    ) ^ h7) << 3)) = make_uint4(da[0], da[1], da[2], da[3]);
    *(uint4*)(bp + (((s0 | 1) ^ h7) << 3)) = make_uint4(db[0], db[1], db[2], db[3]);
  };

  // ---- prologue: stage B tile 0 ----
  loadB(0);
  writeB(bpA);
  __syncthreads();

  int buf = 0;

  // ---- main loop: 4 K-tiles of 64; one barrier per tile; A from global ----
  for (int kt = 0; kt < 4; ++kt) {
    if (kt < 3) loadB(kt + 1);

    #pragma unroll
    for (int ks2 = 0; ks2 < 2; ++ks2) {
      const int kss = kt * 2 + ks2;            // global k-step 0..7
      const int sA  = ks2 * 4 + quad;          // logical k-octet within tile
      short8 af[4], bfr[2];
      #pragma unroll
      for (int f = 0; f < 4; ++f)
        af[f] = *(const short8*)(afrag + kss * 2048 + f * 512);
      #pragma unroll
      for (int g2 = 0; g2 < 2; ++g2) {
        int nl2 = wn * 32 + g2 * 16 + l15;
        bfr[g2] = *(const short8*)(&Blds[buf][nl2 * 64 + ((sA ^ (nl2 & 7)) << 3)]);
      }
      #pragma unroll
      for (int mf = 0; mf < 4; ++mf)
        #pragma unroll
        for (int nf = 0; nf < 2; ++nf)
          acc[mf][nf] = __builtin_amdgcn_mfma_f32_16x16x32_bf16(
              af[mf], bfr[nf], acc[mf][nf], 0, 0, 0);
    }

    if (kt < 3)
      writeB((buf ^ 1) ? bpB : bpA);

    __syncthreads();
    buf ^= 1;
  }

  // ---- epilogue: BN + ReLU + fp32 store ----
  size_t nbase[2];
  #pragma unroll
  for (int nf = 0; nf < 2; ++nf) {
    int ng  = bn * 64 + wn * 32 + nf * 16 + l15;
    int b2  = ng / HW_;
    int hw2 = ng - b2 * HW_;
    nbase[nf] = (size_t)b2 * COUT_ * HW_ + hw2;
  }
  #pragma unroll
  for (int mf = 0; mf < 4; ++mf) {
    int mloc = wm * 64 + mf * 16 + quad * 4;   // local o for reg r=0
    float inv[4], add[4];
    #pragma unroll
    for (int r = 0; r < 4; ++r) {
      inv[r] = bnp[2 * (mloc + r)];
      add[r] = bnp[2 * (mloc + r) + 1];
    }
    size_t obase = (size_t)(bm * 128 + mloc) * HW_;
    #pragma unroll
    for (int nf = 0; nf < 2; ++nf) {
      #pragma unroll
      for (int r = 0; r < 4; ++r) {
        float v = fmaf(acc[mf][nf][r], inv[r], add[r]);
        out[nbase[nf] + obase + (size_t)r * HW_] = fmaxf(v, 0.0f);
      }
    }
  }
}

extern "C" void kernel_launch(void* const* d_in, const int* in_sizes, int n_in,
                              void* d_out, int out_size, void* d_ws, size_t ws_size,
                              hipStream_t stream) {
  const float* x     = (const float*)d_in[0];
  const float* wgt   = (const float*)d_in[1];
  const float* gamma = (const float*)d_in[2];
  const float* beta  = (const float*)d_in[3];
  const float* rmean = (const float*)d_in[4];
  const float* rvar  = (const float*)d_in[5];
  float* out = (float*)d_out;

  prep_weights<<<dim3(256), dim3(256), 0, stream>>>(wgt);
  shiftconv_gemm<<<dim3(3136), dim3(256), 0, stream>>>(x, gamma, beta, rmean, rvar, out);
}